// Round 1
// baseline (382.529 us; speedup 1.0000x reference)
//
#include <hip/hip_runtime.h>

// Problem constants (hardcoded; shapes are fixed by the reference).
#define BATCH 4
#define SQ 2048
#define SKV 2048
#define DMODEL 1024
#define HEADS 16
#define DH 64

typedef __bf16 bf8_t __attribute__((ext_vector_type(8)));
typedef float f4_t __attribute__((ext_vector_type(4)));

static __device__ __forceinline__ unsigned short f2bf(float f) {
  __bf16 h = (__bf16)f;
  return __builtin_bit_cast(unsigned short, h);
}
static __device__ __forceinline__ unsigned int pk2(float a, float b) {
  return (unsigned int)f2bf(a) | ((unsigned int)f2bf(b) << 16);
}

// ---------------------------------------------------------------------------
// Weight transpose+convert: W f32 [K][N] -> WT bf16 [N][K], 64x64 tiles.
// ---------------------------------------------------------------------------
__global__ __launch_bounds__(256) void wtrans_k(const float* __restrict__ W0,
                                                const float* __restrict__ W1,
                                                const float* __restrict__ W2,
                                                const float* __restrict__ W3,
                                                unsigned short* __restrict__ out) {
  __shared__ unsigned short t[64][72];  // +8 pad vs 64 to break write conflicts
  const float* W = blockIdx.z == 0 ? W0 : blockIdx.z == 1 ? W1 : blockIdx.z == 2 ? W2 : W3;
  unsigned short* o = out + (size_t)blockIdx.z * (DMODEL * DMODEL);
  const int tid = threadIdx.x;
  const int k0 = blockIdx.x * 64, n0 = blockIdx.y * 64;
#pragma unroll
  for (int it = 0; it < 4; ++it) {
    int c = tid + it * 256;  // 0..1023 float4 chunks
    int r = c >> 4, q4 = c & 15;
    float4 v = *reinterpret_cast<const float4*>(&W[(size_t)(k0 + r) * DMODEL + n0 + q4 * 4]);
    t[q4 * 4 + 0][r] = f2bf(v.x);
    t[q4 * 4 + 1][r] = f2bf(v.y);
    t[q4 * 4 + 2][r] = f2bf(v.z);
    t[q4 * 4 + 3][r] = f2bf(v.w);
  }
  __syncthreads();
#pragma unroll
  for (int it = 0; it < 2; ++it) {
    int c = tid + it * 256;  // 0..511 8-elem chunks
    int r = c >> 3, s8 = c & 7;
    uint4 pv;
    pv.x = (unsigned)t[r][s8 * 8 + 0] | ((unsigned)t[r][s8 * 8 + 1] << 16);
    pv.y = (unsigned)t[r][s8 * 8 + 2] | ((unsigned)t[r][s8 * 8 + 3] << 16);
    pv.z = (unsigned)t[r][s8 * 8 + 4] | ((unsigned)t[r][s8 * 8 + 5] << 16);
    pv.w = (unsigned)t[r][s8 * 8 + 6] | ((unsigned)t[r][s8 * 8 + 7] << 16);
    *reinterpret_cast<uint4*>(&o[(size_t)(n0 + r) * DMODEL + k0 + s8 * 8]) = pv;
  }
}

// ---------------------------------------------------------------------------
// GEMM: C[M=8192][N=1024] = A[8192][1024] @ BT^T, BT bf16 [N][K].
// MODE 0: A f32  -> C bf16 natural
// MODE 2: A f32  -> C bf16 written transposed per head: VT[b*1024+n][s]
// MODE 3: A bf16 -> C f32 + bias
// 128x128 tile, BK=64, 4 waves, XOR-swizzled LDS.
// ---------------------------------------------------------------------------
template <int MODE>
__global__ __launch_bounds__(256, 2) void gemm_k(const void* __restrict__ Ap,
                                                 const unsigned short* __restrict__ BT,
                                                 void* __restrict__ Cp,
                                                 const float* __restrict__ bias) {
  __shared__ unsigned short As[128 * 64];
  __shared__ unsigned short Bs[128 * 64];
  const int tid = threadIdx.x;
  const int lane = tid & 63, w = tid >> 6;
  const int wr = w >> 1, wc = w & 1;
  const int lr = lane & 15, lg = lane >> 4;
  const int m0 = blockIdx.x * 128, n0 = blockIdx.y * 128;
  f4_t acc[4][4] = {};
  for (int kt = 0; kt < DMODEL / 64; ++kt) {
    const int kb = kt * 64;
#pragma unroll
    for (int ch = 0; ch < 4; ++ch) {
      const int c = tid + ch * 256;          // 0..1023: 8-elem chunks of 128x64 tile
      const int m = c >> 3, k8 = c & 7;
      const int idx = (m * 64 + k8 * 8) ^ ((m & 7) << 3);  // T2 swizzle (16B granules)
      if constexpr (MODE == 3) {
        uint4 v = *reinterpret_cast<const uint4*>((const unsigned short*)Ap +
                                                  (size_t)(m0 + m) * DMODEL + kb + k8 * 8);
        *reinterpret_cast<uint4*>(&As[idx]) = v;
      } else {
        const float* src = (const float*)Ap + (size_t)(m0 + m) * DMODEL + kb + k8 * 8;
        float4 v0 = *reinterpret_cast<const float4*>(src);
        float4 v1 = *reinterpret_cast<const float4*>(src + 4);
        uint4 u;
        u.x = pk2(v0.x, v0.y);
        u.y = pk2(v0.z, v0.w);
        u.z = pk2(v1.x, v1.y);
        u.w = pk2(v1.z, v1.w);
        *reinterpret_cast<uint4*>(&As[idx]) = u;
      }
      uint4 bv = *reinterpret_cast<const uint4*>(&BT[(size_t)(n0 + m) * DMODEL + kb + k8 * 8]);
      *reinterpret_cast<uint4*>(&Bs[idx]) = bv;
    }
    __syncthreads();
#pragma unroll
    for (int ks = 0; ks < 2; ++ks) {
      bf8_t a[4], b[4];
#pragma unroll
      for (int rf = 0; rf < 4; ++rf) {
        const int row = wr * 64 + rf * 16 + lr;
        a[rf] = *reinterpret_cast<const bf8_t*>(
            &As[(row * 64 + ks * 32 + lg * 8) ^ ((row & 7) << 3)]);
      }
#pragma unroll
      for (int cf = 0; cf < 4; ++cf) {
        const int nn = wc * 64 + cf * 16 + lr;
        b[cf] = *reinterpret_cast<const bf8_t*>(
            &Bs[(nn * 64 + ks * 32 + lg * 8) ^ ((nn & 7) << 3)]);
      }
#pragma unroll
      for (int rf = 0; rf < 4; ++rf)
#pragma unroll
        for (int cf = 0; cf < 4; ++cf)
          acc[rf][cf] = __builtin_amdgcn_mfma_f32_16x16x32_bf16(a[rf], b[cf], acc[rf][cf], 0, 0, 0);
    }
    __syncthreads();
  }
  // Epilogue. C/D layout (m89-verified): col = lane&15, row = (lane>>4)*4 + i.
  if constexpr (MODE == 0) {
    unsigned short* C = (unsigned short*)Cp;
#pragma unroll
    for (int rf = 0; rf < 4; ++rf)
#pragma unroll
      for (int cf = 0; cf < 4; ++cf)
#pragma unroll
        for (int i = 0; i < 4; ++i) {
          const int row = m0 + wr * 64 + rf * 16 + lg * 4 + i;
          const int col = n0 + wc * 64 + cf * 16 + lr;
          C[(size_t)row * DMODEL + col] = f2bf(acc[rf][cf][i]);
        }
  } else if constexpr (MODE == 2) {
    unsigned short* VTp = (unsigned short*)Cp;
#pragma unroll
    for (int rf = 0; rf < 4; ++rf)
#pragma unroll
      for (int cf = 0; cf < 4; ++cf) {
        const int row0 = m0 + wr * 64 + rf * 16 + lg * 4;  // 4 consecutive source rows
        const int bb = row0 >> 11, s0 = row0 & 2047;
        const int n = n0 + wc * 64 + cf * 16 + lr;
        ushort4 u;
        u.x = f2bf(acc[rf][cf][0]);
        u.y = f2bf(acc[rf][cf][1]);
        u.z = f2bf(acc[rf][cf][2]);
        u.w = f2bf(acc[rf][cf][3]);
        *reinterpret_cast<ushort4*>(&VTp[(size_t)(bb * 1024 + n) * SKV + s0]) = u;
      }
  } else {  // MODE 3: f32 + bias
    float* C = (float*)Cp;
#pragma unroll
    for (int cf = 0; cf < 4; ++cf) {
      const int col = n0 + wc * 64 + cf * 16 + lr;
      const float bv = bias[col];
#pragma unroll
      for (int rf = 0; rf < 4; ++rf)
#pragma unroll
        for (int i = 0; i < 4; ++i) {
          const int row = m0 + wr * 64 + rf * 16 + lg * 4 + i;
          C[(size_t)row * DMODEL + col] = acc[rf][cf][i] + bv;
        }
    }
  }
}

// ---------------------------------------------------------------------------
// Flash attention: per (b,h), Q[2048,64] x K[2048,64]^T -> softmax -> x V.
// Block: 128 q-rows, 4 waves x 32 rows. KV tiles of 64. VT is [B*H*64][SKV].
// ---------------------------------------------------------------------------
__global__ __launch_bounds__(256, 2) void attn_k(const unsigned short* __restrict__ Qb,
                                                 const unsigned short* __restrict__ Kb,
                                                 const unsigned short* __restrict__ VT,
                                                 unsigned short* __restrict__ AO) {
  __shared__ unsigned short Ks[64 * 64];
  __shared__ unsigned short Vs[64 * 64];
  __shared__ unsigned short Ps[4 * 32 * 64];
  const int tid = threadIdx.x;
  const int lane = tid & 63, w = tid >> 6;
  const int lr = lane & 15, lg = lane >> 4;
  const int q0 = blockIdx.x * 128;
  const int b = blockIdx.y >> 4, h = blockIdx.y & 15;
  const unsigned short* Qp = Qb + (size_t)(b * SQ + q0 + w * 32) * DMODEL + h * DH;
  bf8_t qf[2][2];
#pragma unroll
  for (int rf = 0; rf < 2; ++rf)
#pragma unroll
    for (int ks = 0; ks < 2; ++ks)
      qf[rf][ks] = *reinterpret_cast<const bf8_t*>(
          &Qp[(size_t)(rf * 16 + lr) * DMODEL + ks * 32 + lg * 8]);
  f4_t acc[2][4] = {};
  float mrow[2][4], lsum[2][4];
#pragma unroll
  for (int rf = 0; rf < 2; ++rf)
#pragma unroll
    for (int i = 0; i < 4; ++i) {
      mrow[rf][i] = -1e30f;
      lsum[rf][i] = 0.f;
    }
  const unsigned short* Kh = Kb + (size_t)(b * SKV) * DMODEL + h * DH;
  const unsigned short* Vh = VT + (size_t)(b * 1024 + h * DH) * SKV;
  const float CSC = 0.125f * 1.44269504088896f;  // scale * log2(e)
  for (int kt = 0; kt < SKV / 64; ++kt) {
    const int kv0 = kt * 64;
#pragma unroll
    for (int ch = 0; ch < 2; ++ch) {
      const int c = tid + ch * 256;  // 0..511: 8-elem chunks of 64x64 tiles
      const int r = c >> 3, s8 = c & 7;
      const int idx = (r * 64 + s8 * 8) ^ ((r & 7) << 3);
      *reinterpret_cast<uint4*>(&Ks[idx]) =
          *reinterpret_cast<const uint4*>(&Kh[(size_t)(kv0 + r) * DMODEL + s8 * 8]);
      *reinterpret_cast<uint4*>(&Vs[idx]) =
          *reinterpret_cast<const uint4*>(&Vh[(size_t)r * SKV + kv0 + s8 * 8]);
    }
    __syncthreads();
    // QK^T
    f4_t sc[2][4] = {};
#pragma unroll
    for (int ks = 0; ks < 2; ++ks) {
      bf8_t kf[4];
#pragma unroll
      for (int cf = 0; cf < 4; ++cf) {
        const int rr = cf * 16 + lr;
        kf[cf] = *reinterpret_cast<const bf8_t*>(
            &Ks[(rr * 64 + ks * 32 + lg * 8) ^ ((rr & 7) << 3)]);
      }
#pragma unroll
      for (int rf = 0; rf < 2; ++rf)
#pragma unroll
        for (int cf = 0; cf < 4; ++cf)
          sc[rf][cf] = __builtin_amdgcn_mfma_f32_16x16x32_bf16(qf[rf][ks], kf[cf], sc[rf][cf], 0, 0, 0);
    }
    // online softmax (base-2 domain; scale folded in)
#pragma unroll
    for (int rf = 0; rf < 2; ++rf)
#pragma unroll
      for (int cf = 0; cf < 4; ++cf)
#pragma unroll
        for (int i = 0; i < 4; ++i) sc[rf][cf][i] *= CSC;
#pragma unroll
    for (int rf = 0; rf < 2; ++rf)
#pragma unroll
      for (int i = 0; i < 4; ++i) {
        float t0 = fmaxf(fmaxf(sc[rf][0][i], sc[rf][1][i]), fmaxf(sc[rf][2][i], sc[rf][3][i]));
        t0 = fmaxf(t0, __shfl_xor(t0, 1, 64));
        t0 = fmaxf(t0, __shfl_xor(t0, 2, 64));
        t0 = fmaxf(t0, __shfl_xor(t0, 4, 64));
        t0 = fmaxf(t0, __shfl_xor(t0, 8, 64));
        const float mold = mrow[rf][i];
        const float mnew = fmaxf(mold, t0);
        const float scl = exp2f(mold - mnew);
        float rs = 0.f;
#pragma unroll
        for (int cf = 0; cf < 4; ++cf) {
          const float p = exp2f(sc[rf][cf][i] - mnew);
          sc[rf][cf][i] = p;
          rs += p;
        }
        rs += __shfl_xor(rs, 1, 64);
        rs += __shfl_xor(rs, 2, 64);
        rs += __shfl_xor(rs, 4, 64);
        rs += __shfl_xor(rs, 8, 64);
        lsum[rf][i] = lsum[rf][i] * scl + rs;
        mrow[rf][i] = mnew;
#pragma unroll
        for (int cf = 0; cf < 4; ++cf) acc[rf][cf][i] *= scl;
      }
    // P (C-layout) -> per-wave LDS tile (swizzled), then read as A-frags
#pragma unroll
    for (int rf = 0; rf < 2; ++rf)
#pragma unroll
      for (int cf = 0; cf < 4; ++cf)
#pragma unroll
        for (int i = 0; i < 4; ++i) {
          const int ql = rf * 16 + lg * 4 + i;
          const int kv = cf * 16 + lr;
          Ps[w * 2048 + ((ql * 64 + kv) ^ ((ql & 7) << 3))] = f2bf(sc[rf][cf][i]);
        }
    // PV
#pragma unroll
    for (int ks = 0; ks < 2; ++ks) {
      bf8_t pa[2], vf[4];
#pragma unroll
      for (int rf = 0; rf < 2; ++rf) {
        const int ql = rf * 16 + lr;
        pa[rf] = *reinterpret_cast<const bf8_t*>(
            &Ps[w * 2048 + ((ql * 64 + ks * 32 + lg * 8) ^ ((ql & 7) << 3))]);
      }
#pragma unroll
      for (int cf = 0; cf < 4; ++cf) {
        const int dd = cf * 16 + lr;
        vf[cf] = *reinterpret_cast<const bf8_t*>(
            &Vs[(dd * 64 + ks * 32 + lg * 8) ^ ((dd & 7) << 3)]);
      }
#pragma unroll
      for (int rf = 0; rf < 2; ++rf)
#pragma unroll
        for (int cf = 0; cf < 4; ++cf)
          acc[rf][cf] = __builtin_amdgcn_mfma_f32_16x16x32_bf16(pa[rf], vf[cf], acc[rf][cf], 0, 0, 0);
    }
    __syncthreads();
  }
  unsigned short* Op = AO + (size_t)(b * SQ + q0 + w * 32) * DMODEL + h * DH;
#pragma unroll
  for (int rf = 0; rf < 2; ++rf)
#pragma unroll
    for (int i = 0; i < 4; ++i) {
      const float inv = 1.0f / lsum[rf][i];
#pragma unroll
      for (int cf = 0; cf < 4; ++cf) {
        const int ql = rf * 16 + lg * 4 + i;
        const int col = cf * 16 + lr;
        Op[(size_t)ql * DMODEL + col] = f2bf(acc[rf][cf][i] * inv);
      }
    }
}

// ---------------------------------------------------------------------------
extern "C" void kernel_launch(void* const* d_in, const int* in_sizes, int n_in,
                              void* d_out, int out_size, void* d_ws, size_t ws_size,
                              hipStream_t stream) {
  const float* hs = (const float*)d_in[0];
  const float* ehs = (const float*)d_in[1];
  const float* Wq = (const float*)d_in[2];
  const float* Wk = (const float*)d_in[3];
  const float* Wv = (const float*)d_in[4];
  const float* Wo = (const float*)d_in[5];
  const float* bo = (const float*)d_in[6];
  float* out = (float*)d_out;

  unsigned short* ws = (unsigned short*)d_ws;
  const size_t MM = (size_t)1024 * 1024;
  unsigned short* wT = ws;             // 4 MM: WqT, WkT, WvT, WoT (bf16, [N][K])
  unsigned short* Qb = ws + 4 * MM;    // 8 MM: Q bf16 [B*SQ][1024]
  unsigned short* Kb = Qb + 8 * MM;    // 8 MM: K bf16 [B*SKV][1024]
  unsigned short* VTb = Kb + 8 * MM;   // 8 MM: V^T bf16 [B*H*64][SKV]
  unsigned short* AO = VTb + 8 * MM;   // 8 MM: attn out bf16 [B*SQ][1024]
  // total: 36 MM ushorts = 72 MB of d_ws

  wtrans_k<<<dim3(16, 16, 4), 256, 0, stream>>>(Wq, Wk, Wv, Wo, wT);
  gemm_k<0><<<dim3(64, 8), 256, 0, stream>>>(hs, wT + 0 * MM, Qb, nullptr);
  gemm_k<0><<<dim3(64, 8), 256, 0, stream>>>(ehs, wT + 1 * MM, Kb, nullptr);
  gemm_k<2><<<dim3(64, 8), 256, 0, stream>>>(ehs, wT + 2 * MM, VTb, nullptr);
  attn_k<<<dim3(16, 64), 256, 0, stream>>>(Qb, Kb, VTb, AO);
  gemm_k<3><<<dim3(64, 8), 256, 0, stream>>>(AO, wT + 3 * MM, out, bo);
}

// Round 2
// 224.289 us; speedup vs baseline: 1.7055x; 1.7055x over previous
//
#include <hip/hip_runtime.h>

// Problem constants (hardcoded; shapes are fixed by the reference).
#define BATCH 4
#define SQ 2048
#define SKV 2048
#define DMODEL 1024
#define HEADS 16
#define DH 64

typedef __bf16 bf8_t __attribute__((ext_vector_type(8)));
typedef float f4_t __attribute__((ext_vector_type(4)));
typedef float f16_t __attribute__((ext_vector_type(16)));
typedef unsigned int u32;

static __device__ __forceinline__ unsigned short f2bf(float f) {
  __bf16 h = (__bf16)f;
  return __builtin_bit_cast(unsigned short, h);
}
static __device__ __forceinline__ u32 pk2(float a, float b) {
  return (u32)f2bf(a) | ((u32)f2bf(b) << 16);
}
// async global->LDS, 16B per lane. dst must be the wave-uniform base; HW adds lane*16.
static __device__ __forceinline__ void async16(const unsigned short* g, unsigned short* l) {
  __builtin_amdgcn_global_load_lds((const __attribute__((address_space(1))) unsigned int*)g,
                                   (__attribute__((address_space(3))) unsigned int*)l, 16, 0, 0);
}

// ---------------------------------------------------------------------------
// Weight transpose+convert: W f32 [K][N] -> WT bf16 [N][K], 64x64 tiles.
// Wq (z==0) gets scale*log2(e) folded in so attention needs no logit scaling.
// ---------------------------------------------------------------------------
__global__ __launch_bounds__(256) void wtrans_k(const float* __restrict__ W0,
                                                const float* __restrict__ W1,
                                                const float* __restrict__ W2,
                                                const float* __restrict__ W3,
                                                unsigned short* __restrict__ out) {
  __shared__ unsigned short t[64][72];
  const float* W = blockIdx.z == 0 ? W0 : blockIdx.z == 1 ? W1 : blockIdx.z == 2 ? W2 : W3;
  const float scl = (blockIdx.z == 0) ? 0.125f * 1.44269504088896f : 1.0f;
  unsigned short* o = out + (size_t)blockIdx.z * (DMODEL * DMODEL);
  const int tid = threadIdx.x;
  const int k0 = blockIdx.x * 64, n0 = blockIdx.y * 64;
#pragma unroll
  for (int it = 0; it < 4; ++it) {
    int c = tid + it * 256;
    int r = c >> 4, q4 = c & 15;
    float4 v = *reinterpret_cast<const float4*>(&W[(size_t)(k0 + r) * DMODEL + n0 + q4 * 4]);
    t[q4 * 4 + 0][r] = f2bf(v.x * scl);
    t[q4 * 4 + 1][r] = f2bf(v.y * scl);
    t[q4 * 4 + 2][r] = f2bf(v.z * scl);
    t[q4 * 4 + 3][r] = f2bf(v.w * scl);
  }
  __syncthreads();
#pragma unroll
  for (int it = 0; it < 2; ++it) {
    int c = tid + it * 256;
    int r = c >> 3, s8 = c & 7;
    uint4 pv;
    pv.x = (u32)t[r][s8 * 8 + 0] | ((u32)t[r][s8 * 8 + 1] << 16);
    pv.y = (u32)t[r][s8 * 8 + 2] | ((u32)t[r][s8 * 8 + 3] << 16);
    pv.z = (u32)t[r][s8 * 8 + 4] | ((u32)t[r][s8 * 8 + 5] << 16);
    pv.w = (u32)t[r][s8 * 8 + 6] | ((u32)t[r][s8 * 8 + 7] << 16);
    *reinterpret_cast<uint4*>(&o[(size_t)(n0 + r) * DMODEL + k0 + s8 * 8]) = pv;
  }
}

// ---------------------------------------------------------------------------
// GEMM: C[8192][1024] = A[8192][1024] @ BT^T, BT bf16 [N][K]. (unchanged R1)
// MODE 0: A f32 -> C bf16 | MODE 2: A f32 -> C=V^T per head | MODE 3: A bf16 -> f32+bias
// ---------------------------------------------------------------------------
template <int MODE>
__global__ __launch_bounds__(256, 2) void gemm_k(const void* __restrict__ Ap,
                                                 const unsigned short* __restrict__ BT,
                                                 void* __restrict__ Cp,
                                                 const float* __restrict__ bias) {
  __shared__ unsigned short As[128 * 64];
  __shared__ unsigned short Bs[128 * 64];
  const int tid = threadIdx.x;
  const int lane = tid & 63, w = tid >> 6;
  const int wr = w >> 1, wc = w & 1;
  const int lr = lane & 15, lg = lane >> 4;
  const int m0 = blockIdx.x * 128, n0 = blockIdx.y * 128;
  f4_t acc[4][4] = {};
  for (int kt = 0; kt < DMODEL / 64; ++kt) {
    const int kb = kt * 64;
#pragma unroll
    for (int ch = 0; ch < 4; ++ch) {
      const int c = tid + ch * 256;
      const int m = c >> 3, k8 = c & 7;
      const int idx = (m * 64 + k8 * 8) ^ ((m & 7) << 3);
      if constexpr (MODE == 3) {
        uint4 v = *reinterpret_cast<const uint4*>((const unsigned short*)Ap +
                                                  (size_t)(m0 + m) * DMODEL + kb + k8 * 8);
        *reinterpret_cast<uint4*>(&As[idx]) = v;
      } else {
        const float* src = (const float*)Ap + (size_t)(m0 + m) * DMODEL + kb + k8 * 8;
        float4 v0 = *reinterpret_cast<const float4*>(src);
        float4 v1 = *reinterpret_cast<const float4*>(src + 4);
        uint4 u;
        u.x = pk2(v0.x, v0.y);
        u.y = pk2(v0.z, v0.w);
        u.z = pk2(v1.x, v1.y);
        u.w = pk2(v1.z, v1.w);
        *reinterpret_cast<uint4*>(&As[idx]) = u;
      }
      uint4 bv = *reinterpret_cast<const uint4*>(&BT[(size_t)(n0 + m) * DMODEL + kb + k8 * 8]);
      *reinterpret_cast<uint4*>(&Bs[idx]) = bv;
    }
    __syncthreads();
#pragma unroll
    for (int ks = 0; ks < 2; ++ks) {
      bf8_t a[4], b[4];
#pragma unroll
      for (int rf = 0; rf < 4; ++rf) {
        const int row = wr * 64 + rf * 16 + lr;
        a[rf] = *reinterpret_cast<const bf8_t*>(
            &As[(row * 64 + ks * 32 + lg * 8) ^ ((row & 7) << 3)]);
      }
#pragma unroll
      for (int cf = 0; cf < 4; ++cf) {
        const int nn = wc * 64 + cf * 16 + lr;
        b[cf] = *reinterpret_cast<const bf8_t*>(
            &Bs[(nn * 64 + ks * 32 + lg * 8) ^ ((nn & 7) << 3)]);
      }
#pragma unroll
      for (int rf = 0; rf < 4; ++rf)
#pragma unroll
        for (int cf = 0; cf < 4; ++cf)
          acc[rf][cf] = __builtin_amdgcn_mfma_f32_16x16x32_bf16(a[rf], b[cf], acc[rf][cf], 0, 0, 0);
    }
    __syncthreads();
  }
  if constexpr (MODE == 0) {
    unsigned short* C = (unsigned short*)Cp;
#pragma unroll
    for (int rf = 0; rf < 4; ++rf)
#pragma unroll
      for (int cf = 0; cf < 4; ++cf)
#pragma unroll
        for (int i = 0; i < 4; ++i) {
          const int row = m0 + wr * 64 + rf * 16 + lg * 4 + i;
          const int col = n0 + wc * 64 + cf * 16 + lr;
          C[(size_t)row * DMODEL + col] = f2bf(acc[rf][cf][i]);
        }
  } else if constexpr (MODE == 2) {
    unsigned short* VTp = (unsigned short*)Cp;
#pragma unroll
    for (int rf = 0; rf < 4; ++rf)
#pragma unroll
      for (int cf = 0; cf < 4; ++cf) {
        const int row0 = m0 + wr * 64 + rf * 16 + lg * 4;
        const int bb = row0 >> 11, s0 = row0 & 2047;
        const int n = n0 + wc * 64 + cf * 16 + lr;
        ushort4 u;
        u.x = f2bf(acc[rf][cf][0]);
        u.y = f2bf(acc[rf][cf][1]);
        u.z = f2bf(acc[rf][cf][2]);
        u.w = f2bf(acc[rf][cf][3]);
        *reinterpret_cast<ushort4*>(&VTp[(size_t)(bb * 1024 + n) * SKV + s0]) = u;
      }
  } else {
    float* C = (float*)Cp;
#pragma unroll
    for (int cf = 0; cf < 4; ++cf) {
      const int col = n0 + wc * 64 + cf * 16 + lr;
      const float bv = bias[col];
#pragma unroll
      for (int rf = 0; rf < 4; ++rf)
#pragma unroll
        for (int i = 0; i < 4; ++i) {
          const int row = m0 + wr * 64 + rf * 16 + lg * 4 + i;
          C[(size_t)row * DMODEL + col] = acc[rf][cf][i] + bv;
        }
    }
  }
}

// ---------------------------------------------------------------------------
// Flash attention, m214-style 32x32 structure (D=64):
//  - swapped QK^T: S^T = mfma(A=K, B=Q); lane owns row q=lane&31 (32 regs)
//  - in-register softmax; defer-max (THR=8); scale*log2e pre-folded into Wq
//  - P -> PV B-frags via cvt_pk + v_permlane32_swap (no LDS round-trip)
//  - PV: O^T = mfma(A=V^T, B=P); V^T comes from the MODE-2 GEMM
//  - K/V staged via global_load_lds (pre-swizzled source), double-buffered,
//    1 barrier per KV-tile; XCD-swizzled block ids (8 heads per XCD -> L2)
// 4 waves x 32 q-rows, KVBLK=64, grid 1024.
// ---------------------------------------------------------------------------
__global__ __launch_bounds__(256, 4) void attn_k(const unsigned short* __restrict__ Qb,
                                                 const unsigned short* __restrict__ Kb,
                                                 const unsigned short* __restrict__ VT,
                                                 unsigned short* __restrict__ AO) {
  __shared__ unsigned short Ks[2][64 * 64];
  __shared__ unsigned short Vs[2][64 * 64];
  const int tid = threadIdx.x;
  const int lane = tid & 63, w = tid >> 6;
  const int rw = lane & 31, hi = lane >> 5;

  // bijective XCD swizzle: 1024 blocks, 8 XCDs, 128 blocks each -> 8 heads/XCD
  const int bid = blockIdx.x;
  const int swz = (bid & 7) * 128 + (bid >> 3);
  const int hl = swz >> 4;  // 0..63  (b*16+h)
  const int qb = swz & 15;  // 0..15  q-block of 128 rows
  const int b = hl >> 4, h = hl & 15;
  const int q0 = qb * 128 + w * 32;

  // Q B-frags: col=q(=rw), k = d = 16f + 8hi + j  (Wq pre-scaled)
  const unsigned short* Qp = Qb + ((size_t)(b * SQ + q0 + rw)) * DMODEL + h * DH + hi * 8;
  bf8_t qf[4];
#pragma unroll
  for (int f = 0; f < 4; ++f)
    qf[f] = *reinterpret_cast<const bf8_t*>(Qp + 16 * f);

  f16_t acc0 = {}, acc1 = {};
  float mrow = -1e30f, lsum = 0.f;

  const unsigned short* Kh = Kb + (size_t)(b * SKV) * DMODEL + h * DH;
  const unsigned short* Vh = VT + (size_t)(b * 1024 + h * DH) * SKV;

  // stage KV tile kt into buffer bf (pre-swizzled source, linear LDS dest)
  auto stage = [&](int bf, int kt) {
    const int kv0 = kt * 64;
#pragma unroll
    for (int ch = 0; ch < 2; ++ch) {
      const int g = ch * 256 + tid;
      const int r = g >> 3, s8 = (g & 7) ^ (r & 7);
      unsigned short* kdst = &Ks[bf][(ch * 256 + w * 64) * 8];
      unsigned short* vdst = &Vs[bf][(ch * 256 + w * 64) * 8];
      async16(Kh + (size_t)(kv0 + r) * DMODEL + s8 * 8, kdst);
      async16(Vh + (size_t)r * SKV + kv0 + s8 * 8, vdst);
    }
  };

  stage(0, 0);
  __syncthreads();  // drains vmcnt(0)

  int cur = 0;
  for (int kt = 0; kt < SKV / 64; ++kt) {
    if (kt + 1 < SKV / 64) stage(cur ^ 1, kt + 1);

    // ---- QK^T: S^T[kv][q], two 32-kv blocks ----
    f16_t s0 = {}, s1 = {};
    __builtin_amdgcn_s_setprio(1);
#pragma unroll
    for (int f = 0; f < 4; ++f) {
      const int gcol = ((2 * f + hi) ^ (rw & 7)) * 8;
      bf8_t k0 = *reinterpret_cast<const bf8_t*>(&Ks[cur][rw * 64 + gcol]);
      bf8_t k1 = *reinterpret_cast<const bf8_t*>(&Ks[cur][(rw + 32) * 64 + gcol]);
      s0 = __builtin_amdgcn_mfma_f32_32x32x16_bf16(k0, qf[f], s0, 0, 0, 0);
      s1 = __builtin_amdgcn_mfma_f32_32x32x16_bf16(k1, qf[f], s1, 0, 0, 0);
    }
    __builtin_amdgcn_s_setprio(0);

    // ---- online softmax, fully in-register (base-2 domain) ----
    float pmax = -1e30f;
#pragma unroll
    for (int i = 0; i < 16; ++i) pmax = fmaxf(pmax, fmaxf(s0[i], s1[i]));
    pmax = fmaxf(pmax, __shfl_xor(pmax, 32, 64));
    if (__any(pmax > mrow + 8.f)) {  // rescale (rare after tile 0: defer-max)
      const float mnew = fmaxf(mrow, pmax);
      const float scl = __builtin_amdgcn_exp2f(mrow - mnew);
      lsum *= scl;
#pragma unroll
      for (int i = 0; i < 16; ++i) {
        acc0[i] *= scl;
        acc1[i] *= scl;
      }
      mrow = mnew;
    }
    float sum = 0.f;
#pragma unroll
    for (int i = 0; i < 16; ++i) {
      s0[i] = __builtin_amdgcn_exp2f(s0[i] - mrow);
      sum += s0[i];
    }
#pragma unroll
    for (int i = 0; i < 16; ++i) {
      s1[i] = __builtin_amdgcn_exp2f(s1[i] - mrow);
      sum += s1[i];
    }
    lsum += sum;  // per-lane partial; partner-half added in epilogue

    // ---- PV: O^T += V^T x P, per 32-kv block ----
    __builtin_amdgcn_s_setprio(1);
#pragma unroll
    for (int kb = 0; kb < 2; ++kb) {
      const f16_t& sv = kb ? s1 : s0;
      // P -> B-frags (col=q, k=kv=8hi+j) via cvt_pk + permlane32_swap (T12)
      bf8_t pf[2];
      {
        u32 w0 = pk2(sv[0], sv[1]), w2 = pk2(sv[4], sv[5]);
        asm volatile("v_permlane32_swap_b32 %0, %1" : "+v"(w0), "+v"(w2));
        u32 w1 = pk2(sv[2], sv[3]), w3 = pk2(sv[6], sv[7]);
        asm volatile("v_permlane32_swap_b32 %0, %1" : "+v"(w1), "+v"(w3));
        uint4 t0 = {w0, w1, w2, w3};
        pf[0] = __builtin_bit_cast(bf8_t, t0);
        u32 x0 = pk2(sv[8], sv[9]), x2 = pk2(sv[12], sv[13]);
        asm volatile("v_permlane32_swap_b32 %0, %1" : "+v"(x0), "+v"(x2));
        u32 x1 = pk2(sv[10], sv[11]), x3 = pk2(sv[14], sv[15]);
        asm volatile("v_permlane32_swap_b32 %0, %1" : "+v"(x1), "+v"(x3));
        uint4 t1 = {x0, x1, x2, x3};
        pf[1] = __builtin_bit_cast(bf8_t, t1);
      }
#pragma unroll
      for (int s = 0; s < 2; ++s) {
        const int g = 4 * kb + 2 * s + hi;
        const int gcol = ((g ^ (rw & 7)) * 8);
        bf8_t v0 = *reinterpret_cast<const bf8_t*>(&Vs[cur][rw * 64 + gcol]);
        bf8_t v1 = *reinterpret_cast<const bf8_t*>(&Vs[cur][(rw + 32) * 64 + gcol]);
        acc0 = __builtin_amdgcn_mfma_f32_32x32x16_bf16(v0, pf[s], acc0, 0, 0, 0);
        acc1 = __builtin_amdgcn_mfma_f32_32x32x16_bf16(v1, pf[s], acc1, 0, 0, 0);
      }
    }
    __builtin_amdgcn_s_setprio(0);

    __syncthreads();  // stage complete (vmcnt) + all reads of cur done
    cur ^= 1;
  }

  // ---- epilogue: normalize, write O[q][d] (lane holds O^T col q=rw) ----
  const float lrow = lsum + __shfl_xor(lsum, 32, 64);
  const float inv = 1.f / lrow;
  unsigned short* Op = AO + ((size_t)(b * SQ + q0 + rw)) * DMODEL + h * DH;
#pragma unroll
  for (int db = 0; db < 2; ++db) {
    const f16_t& A = db ? acc1 : acc0;
#pragma unroll
    for (int r = 0; r < 16; r += 2) {
      const int d = db * 32 + (r & 3) + 8 * (r >> 2) + 4 * hi;
      *reinterpret_cast<u32*>(Op + d) = pk2(A[r] * inv, A[r + 1] * inv);
    }
  }
}

// ---------------------------------------------------------------------------
extern "C" void kernel_launch(void* const* d_in, const int* in_sizes, int n_in,
                              void* d_out, int out_size, void* d_ws, size_t ws_size,
                              hipStream_t stream) {
  const float* hs = (const float*)d_in[0];
  const float* ehs = (const float*)d_in[1];
  const float* Wq = (const float*)d_in[2];
  const float* Wk = (const float*)d_in[3];
  const float* Wv = (const float*)d_in[4];
  const float* Wo = (const float*)d_in[5];
  const float* bo = (const float*)d_in[6];
  float* out = (float*)d_out;

  unsigned short* ws = (unsigned short*)d_ws;
  const size_t MM = (size_t)1024 * 1024;
  unsigned short* wT = ws;             // 4 MM: WqT(scaled), WkT, WvT, WoT
  unsigned short* Qb = ws + 4 * MM;    // 8 MM: Q bf16 [B*SQ][1024]
  unsigned short* Kb = Qb + 8 * MM;    // 8 MM: K bf16 [B*SKV][1024]
  unsigned short* VTb = Kb + 8 * MM;   // 8 MM: V^T bf16 [B*H*64][SKV]
  unsigned short* AO = VTb + 8 * MM;   // 8 MM: attn out bf16 [B*SQ][1024]

  wtrans_k<<<dim3(16, 16, 4), 256, 0, stream>>>(Wq, Wk, Wv, Wo, wT);
  gemm_k<0><<<dim3(64, 8), 256, 0, stream>>>(hs, wT + 0 * MM, Qb, nullptr);
  gemm_k<0><<<dim3(64, 8), 256, 0, stream>>>(ehs, wT + 1 * MM, Kb, nullptr);
  gemm_k<2><<<dim3(64, 8), 256, 0, stream>>>(ehs, wT + 2 * MM, VTb, nullptr);
  attn_k<<<dim3(1024), 256, 0, stream>>>(Qb, Kb, VTb, AO);
  gemm_k<3><<<dim3(64, 8), 256, 0, stream>>>(AO, wT + 3 * MM, out, bo);
}